// Round 2
// baseline (2819.442 us; speedup 1.0000x reference)
//
#include <hip/hip_runtime.h>

#define HH 180
#define WW 180
#define HWN 32400
#define CC 128
#define CINN 384
#define KK 10
#define PP 200
#define NHH 8
#define BB 2
#define NTOT 324000  // K*H*W per batch

// ------ weight transpose: wt[cin][tap][cout] <- w[cout][cin][tap] -------------
__global__ void k_transw(const float* __restrict__ w, float* __restrict__ wt, int cin) {
    int idx = blockIdx.x * 256 + threadIdx.x;
    int total = cin * 9 * 128;
    if (idx >= total) return;
    int ci = idx / (9 * 128);
    int rem = idx % (9 * 128);
    int ktap = rem / 128, co = rem % 128;
    wt[idx] = w[((size_t)co * cin + ci) * 9 + ktap];
}

// ------ implicit-GEMM 3x3 conv: 128 cout x 64 px tile, 128 thr, 64 acc --------
// thread: cg=tid&15 -> couts {cg*4..+3} and {64+cg*4..+3}; pg=tid>>4 -> px pg*8..+7
// cin-chunk = 4; accumulation order over (c,ky,kx) identical to round-1 kernel.
template<int CINT, int EPI>
__global__ __launch_bounds__(128) void k_conv3x3(
    const float* __restrict__ x, const float* __restrict__ wt,
    const float* __restrict__ bias, const float* __restrict__ g,
    const float* __restrict__ beta, float* __restrict__ out)
{
    __shared__ float xs[4][3][68];        // 4 cin x 3 rows x 66(+pad2) px
    __shared__ float wsm[4][9][128];      // 4 cin x 9 taps x 128 cout
    const int tid = threadIdx.x;
    const int b = blockIdx.z, oy = blockIdx.y, ox0 = blockIdx.x * 64;
    const int cg = tid & 15, pg = tid >> 4;
    float acc[2][4][8];
#pragma unroll
    for (int h = 0; h < 2; ++h)
#pragma unroll
        for (int i = 0; i < 4; ++i)
#pragma unroll
            for (int j = 0; j < 8; ++j) acc[h][i][j] = 0.f;

    for (int c0 = 0; c0 < CINT; c0 += 4) {
        // stage weights: contiguous 4*9*128 floats from wt[c0*1152]
        {
            const float4* src = (const float4*)(wt + (size_t)c0 * 1152);
            float4* dst = (float4*)&wsm[0][0][0];
            for (int s = tid; s < 1152; s += 128) dst[s] = src[s];
        }
        // stage x halo tile: 4 cin x 3 rows x 66 px
        for (int s = tid; s < 792; s += 128) {
            int c = s / 198, rem = s % 198, r = rem / 66, i = rem % 66;
            int row = oy + r - 1, px = ox0 + i - 1;
            float v = 0.f;
            if ((unsigned)row < (unsigned)HH && (unsigned)px < (unsigned)WW)
                v = x[(((size_t)b * CINT + c0 + c) * HH + row) * WW + px];
            xs[c][r][i] = v;
        }
        __syncthreads();
#pragma unroll
        for (int c = 0; c < 4; ++c) {
#pragma unroll
            for (int ky = 0; ky < 3; ++ky) {
                float xr[10];
                const float4 t0 = *(const float4*)&xs[c][ky][pg * 8];
                const float4 t1 = *(const float4*)&xs[c][ky][pg * 8 + 4];
                xr[0] = t0.x; xr[1] = t0.y; xr[2] = t0.z; xr[3] = t0.w;
                xr[4] = t1.x; xr[5] = t1.y; xr[6] = t1.z; xr[7] = t1.w;
                xr[8] = xs[c][ky][pg * 8 + 8];
                xr[9] = xs[c][ky][pg * 8 + 9];
#pragma unroll
                for (int kx = 0; kx < 3; ++kx) {
                    const float4 wa = *(const float4*)&wsm[c][ky * 3 + kx][cg * 4];
                    const float4 wb = *(const float4*)&wsm[c][ky * 3 + kx][64 + cg * 4];
#pragma unroll
                    for (int j = 0; j < 8; ++j) {
                        const float xv = xr[kx + j];
                        acc[0][0][j] += wa.x * xv;
                        acc[0][1][j] += wa.y * xv;
                        acc[0][2][j] += wa.z * xv;
                        acc[0][3][j] += wa.w * xv;
                        acc[1][0][j] += wb.x * xv;
                        acc[1][1][j] += wb.y * xv;
                        acc[1][2][j] += wb.z * xv;
                        acc[1][3][j] += wb.w * xv;
                    }
                }
            }
        }
        __syncthreads();
    }
#pragma unroll
    for (int h = 0; h < 2; ++h)
#pragma unroll
    for (int i = 0; i < 4; ++i) {
        const int cout = h * 64 + cg * 4 + i;
        const float bv = bias[cout];
        float gv = 0.f, bev = 0.f;
        if constexpr (EPI) { gv = g[cout]; bev = beta[cout]; }
#pragma unroll
        for (int j = 0; j < 8; ++j) {
            const int px = ox0 + pg * 8 + j;
            if (px < WW) {
                float v = acc[h][i][j] + bv;
                if constexpr (EPI) v = fmaxf(gv * v + bev, 0.f);
                out[(((size_t)b * 128 + cout) * HH + oy) * WW + px] = v;
            }
        }
    }
}

// ---------------- heatmap conv2 (128->10) + sigmoid ---------------------------
__global__ __launch_bounds__(192) void k_convhm2(const float* __restrict__ h1,
    const float* __restrict__ w, const float* __restrict__ bias,
    float* __restrict__ hm_raw)
{
    __shared__ float xs[8][3][184];
    __shared__ float ws[11520];
    const int tid = threadIdx.x, oy = blockIdx.x, b = blockIdx.y;
    for (int s = tid; s < 11520; s += 192) ws[s] = w[s];
    float acc[10];
#pragma unroll
    for (int o = 0; o < 10; ++o) acc[o] = 0.f;
    for (int c0 = 0; c0 < 128; c0 += 8) {
        __syncthreads();
        for (int s = tid; s < 4368; s += 192) {
            int c = s / 546, rem = s % 546, r = rem / 182, i = rem % 182;
            int row = oy + r - 1, px = i - 1;
            float v = 0.f;
            if ((unsigned)row < (unsigned)HH && (unsigned)px < (unsigned)WW)
                v = h1[(((size_t)b * 128 + c0 + c) * HH + row) * WW + px];
            xs[c][r][i] = v;
        }
        __syncthreads();
        if (tid < 180) {
#pragma unroll
            for (int c = 0; c < 8; ++c) {
#pragma unroll
                for (int ky = 0; ky < 3; ++ky) {
                    const float x0 = xs[c][ky][tid];
                    const float x1 = xs[c][ky][tid + 1];
                    const float x2 = xs[c][ky][tid + 2];
#pragma unroll
                    for (int o = 0; o < 10; ++o) {
                        const float* wp = &ws[((size_t)o * 128 + c0 + c) * 9 + ky * 3];
                        acc[o] += x0 * wp[0] + x1 * wp[1] + x2 * wp[2];
                    }
                }
            }
        }
    }
    if (tid < 180) {
#pragma unroll
        for (int o = 0; o < 10; ++o) {
            const float z = acc[o] + bias[o];
            hm_raw[(((size_t)b * 10 + o) * HH + oy) * WW + tid] = 1.f / (1.f + expf(-z));
        }
    }
}

// ---------------- 3x3 local-max NMS mask --------------------------------------
__global__ void k_nms(const float* __restrict__ hm, float* __restrict__ out) {
    int i = blockIdx.x * 256 + threadIdx.x;
    if (i >= BB * KK * HWN) return;
    int xx = i % WW, yy = (i / WW) % HH, ck = i / HWN;
    float v = hm[i], m = v;
    for (int dy = -1; dy <= 1; ++dy) {
        int ny = yy + dy;
        if ((unsigned)ny >= (unsigned)HH) continue;
        for (int dx = -1; dx <= 1; ++dx) {
            int nx = xx + dx;
            if ((unsigned)nx >= (unsigned)WW) continue;
            m = fmaxf(m, hm[(size_t)ck * HWN + ny * WW + nx]);
        }
    }
    out[i] = (v == m) ? v : 0.f;
}

// ---------------- exact top-200 (radix select + bitonic sort) -----------------
__global__ __launch_bounds__(1024) void k_topk(const float* __restrict__ hm_msk,
                                               int* __restrict__ top_idx) {
    const int b = blockIdx.x, tid = threadIdx.x;
    const float* src = hm_msk + (size_t)b * NTOT;
    __shared__ unsigned hist[256];
    __shared__ unsigned sh_prefix, sh_rem, sh_cnt;
    __shared__ unsigned long long buf[1024];
    if (tid == 0) { sh_prefix = 0u; sh_rem = 200u; sh_cnt = 0u; }
    __syncthreads();
    for (int r = 3; r >= 0; --r) {
        if (tid < 256) hist[tid] = 0u;
        __syncthreads();
        const unsigned pfx = sh_prefix;
        for (int i = tid; i < NTOT; i += 1024) {
            const unsigned key = __float_as_uint(src[i]);
            const bool ok = (r == 3) || ((key >> ((r + 1) * 8)) == pfx);
            if (ok) atomicAdd(&hist[(key >> (r * 8)) & 255u], 1u);
        }
        __syncthreads();
        if (tid == 0) {
            unsigned acc = 0, rem = sh_rem;
            int v;
            for (v = 255; v >= 0; --v) {
                const unsigned h = hist[v];
                if (acc + h >= rem) break;
                acc += h;
            }
            if (v < 0) v = 0;  // safety (cannot happen)
            sh_prefix = (pfx << 8) | (unsigned)v;
            sh_rem = rem - acc;
        }
        __syncthreads();
    }
    const unsigned pivot = sh_prefix;
    for (int i = tid; i < NTOT; i += 1024) {
        const unsigned key = __float_as_uint(src[i]);
        if (key >= pivot) {
            const unsigned pos = atomicAdd(&sh_cnt, 1u);
            if (pos < 1024u)
                buf[pos] = (((unsigned long long)(~key)) << 32) | (unsigned)i;
        }
    }
    __syncthreads();
    const unsigned cnt = sh_cnt < 1024u ? sh_cnt : 1024u;
    if ((unsigned)tid >= cnt) buf[tid] = 0xFFFFFFFFFFFFFFFFull;
    __syncthreads();
    for (int k = 2; k <= 1024; k <<= 1) {
        for (int j = k >> 1; j > 0; j >>= 1) {
            const int ixj = tid ^ j;
            if (ixj > tid) {
                const unsigned long long a = buf[tid], c = buf[ixj];
                const bool up = ((tid & k) == 0);
                if ((a > c) == up) { buf[tid] = c; buf[ixj] = a; }
            }
            __syncthreads();
        }
    }
    if (tid < 200) {
        const int idx = (int)(buf[tid] & 0xFFFFFFFFull);
        top_idx[b * 200 + tid] = idx % HWN;
    }
}

// ---------------- kpe for all BEV positions (stored transposed [128][HW]) -----
__global__ __launch_bounds__(128) void k_kpe(const float* __restrict__ w1,
    const float* __restrict__ b1, const float* __restrict__ w2,
    const float* __restrict__ b2, float* __restrict__ kpeT)
{
    __shared__ float pe[8][258];
    __shared__ float hid[8][130];
    const int tid = threadIdx.x;
    const int pos0 = blockIdx.x * 8;
    const int half = tid >> 6, m = tid & 63;
    const float dimt = 1.f + (float)m * 0.015625f;
#pragma unroll
    for (int p = 0; p < 8; ++p) {
        const int pos = pos0 + p;
        const int i = pos / WW, j = pos % WW;
        const float coord = (half == 0) ? ((float)j + 0.5f) * (1.f / 180.f)
                                        : ((float)i + 0.5f) * (1.f / 180.f);
        const float arg = (coord * 6.2831855f) / dimt;
        pe[p][half * 128 + 2 * m]     = sinf(arg);
        pe[p][half * 128 + 2 * m + 1] = cosf(arg);
    }
    __syncthreads();
    float acc[8];
#pragma unroll
    for (int p = 0; p < 8; ++p) acc[p] = b1[tid];
    for (int k = 0; k < 256; ++k) {
        const float w = w1[k * 128 + tid];
#pragma unroll
        for (int p = 0; p < 8; ++p) acc[p] += pe[p][k] * w;
    }
#pragma unroll
    for (int p = 0; p < 8; ++p) hid[p][tid] = fmaxf(acc[p], 0.f);
    __syncthreads();
#pragma unroll
    for (int p = 0; p < 8; ++p) acc[p] = b2[tid];
    for (int k = 0; k < 128; ++k) {
        const float w = w2[k * 128 + tid];
#pragma unroll
        for (int p = 0; p < 8; ++p) acc[p] += hid[p][k] * w;
    }
#pragma unroll
    for (int p = 0; p < 8; ++p) kpeT[(size_t)tid * HWN + pos0 + p] = acc[p];
}

// ---------------- gather q0/qpe/q_hm ------------------------------------------
__global__ __launch_bounds__(128) void k_gather(const float* __restrict__ feat,
    const float* __restrict__ kpeT, const float* __restrict__ hm_msk,
    const int* __restrict__ top_idx, float* __restrict__ q0,
    float* __restrict__ qpe, float* __restrict__ qhm)
{
    const int p = blockIdx.x, b = blockIdx.y, c = threadIdx.x;
    const int idx = top_idx[b * 200 + p];
    q0[((size_t)b * 200 + p) * 128 + c]  = feat[((size_t)b * 128 + c) * HWN + idx];
    qpe[((size_t)b * 200 + p) * 128 + c] = kpeT[(size_t)c * HWN + idx];
    if (c < 10)
        qhm[((size_t)b * 10 + c) * 200 + p] = hm_msk[((size_t)b * 10 + c) * HWN + idx];
}

// ---------------- self-attn qkv projection ------------------------------------
__global__ __launch_bounds__(128) void k_proj_self(const float* __restrict__ q0,
    const float* __restrict__ qpe, const float* __restrict__ w,
    const float* __restrict__ bias, float* __restrict__ qh,
    float* __restrict__ kh, float* __restrict__ vh)
{
    __shared__ float in0[128], in1[128];
    const int p = blockIdx.x, b = blockIdx.y, c = threadIdx.x;
    const size_t base = ((size_t)b * 200 + p) * 128;
    const float a = q0[base + c], pe = qpe[base + c];
    in0[c] = a + pe; in1[c] = a;
    __syncthreads();
    float aq = bias[c], ak = bias[128 + c], av = bias[256 + c];
    for (int k = 0; k < 128; ++k) {
        const float i0 = in0[k];
        aq += i0 * w[k * 128 + c];
        ak += i0 * w[16384 + k * 128 + c];
        av += in1[k] * w[32768 + k * 128 + c];
    }
    qh[base + c] = aq; kh[base + c] = ak; vh[base + c] = av;
}

// ---------------- self-attention (200 keys) -----------------------------------
__global__ __launch_bounds__(256) void k_attn_self(const float* __restrict__ qh,
    const float* __restrict__ kh, const float* __restrict__ vh, float* __restrict__ o)
{
    __shared__ float ks[200][16], vs[200][16];
    const int h = blockIdx.x, b = blockIdx.y, tid = threadIdx.x;
    for (int s = tid; s < 3200; s += 256) {
        const int n = s >> 4, d = s & 15;
        ks[n][d] = kh[((size_t)b * 200 + n) * 128 + h * 16 + d];
        vs[n][d] = vh[((size_t)b * 200 + n) * 128 + h * 16 + d];
    }
    __syncthreads();
    if (tid < 200) {
        float q[16];
#pragma unroll
        for (int d = 0; d < 16; ++d)
            q[d] = qh[((size_t)b * 200 + tid) * 128 + h * 16 + d] * 0.25f;
        float mmax = -1e30f, l = 0.f, acc[16];
#pragma unroll
        for (int d = 0; d < 16; ++d) acc[d] = 0.f;
        for (int j = 0; j < 200; ++j) {
            float s = 0.f;
#pragma unroll
            for (int d = 0; d < 16; ++d) s += q[d] * ks[j][d];
            const float mn = fmaxf(mmax, s);
            const float corr = __expf(mmax - mn);
            const float pv = __expf(s - mn);
            l = l * corr + pv;
#pragma unroll
            for (int d = 0; d < 16; ++d) acc[d] = acc[d] * corr + pv * vs[j][d];
            mmax = mn;
        }
#pragma unroll
        for (int d = 0; d < 16; ++d)
            o[((size_t)b * 200 + tid) * 128 + h * 16 + d] = acc[d] / l;
    }
}

// ---------------- out-projection + residual + LayerNorm -----------------------
__global__ __launch_bounds__(128) void k_proj_ln(const float* __restrict__ src,
    const float* __restrict__ W, const float* __restrict__ bW,
    const float* __restrict__ resid, const float* __restrict__ g,
    const float* __restrict__ lb, float* __restrict__ out)
{
    __shared__ float sIn[128];
    __shared__ float rbuf[4];
    const int p = blockIdx.x, b = blockIdx.y, c = threadIdx.x;
    const size_t base = ((size_t)b * 200 + p) * 128;
    sIn[c] = src[base + c];
    __syncthreads();
    float v = bW[c] + resid[base + c];
    for (int k = 0; k < 128; ++k) v += sIn[k] * W[k * 128 + c];
    float s = v;
#pragma unroll
    for (int off = 32; off >= 1; off >>= 1) s += __shfl_xor(s, off);
    if ((c & 63) == 0) rbuf[c >> 6] = s;
    __syncthreads();
    const float mean = (rbuf[0] + rbuf[1]) * (1.f / 128.f);
    const float dv = v - mean;
    float s2 = dv * dv;
#pragma unroll
    for (int off = 32; off >= 1; off >>= 1) s2 += __shfl_xor(s2, off);
    if ((c & 63) == 0) rbuf[2 + (c >> 6)] = s2;
    __syncthreads();
    const float var = (rbuf[2] + rbuf[3]) * (1.f / 128.f);
    out[base + c] = g[c] * dv / sqrtf(var + 1e-5f) + lb[c];
}

// ---------------- cross-attn query projection ---------------------------------
__global__ __launch_bounds__(128) void k_proj_q(const float* __restrict__ q1n,
    const float* __restrict__ qpe, const float* __restrict__ w,
    const float* __restrict__ bw, float* __restrict__ out)
{
    __shared__ float in0[128];
    const int p = blockIdx.x, b = blockIdx.y, c = threadIdx.x;
    const size_t base = ((size_t)b * 200 + p) * 128;
    in0[c] = q1n[base + c] + qpe[base + c];
    __syncthreads();
    float a = bw[c];
    for (int k = 0; k < 128; ++k) a += in0[k] * w[k * 128 + c];
    out[base + c] = a;
}

// ---------------- cross K/V projection over HW --------------------------------
__global__ __launch_bounds__(256) void k_kv_cross(const float* __restrict__ feat,
    const float* __restrict__ kpeT, const float* __restrict__ w,
    const float* __restrict__ bias, float* __restrict__ kh, float* __restrict__ vh)
{
    __shared__ float as[32][68];
    __shared__ float wk[32][128], wv[32][128];
    const int tid = threadIdx.x, n0 = blockIdx.x * 64, b = blockIdx.y;
    const int cg = tid & 31, ng = tid >> 5;
    float ak[4][8], av[4][8];
#pragma unroll
    for (int i = 0; i < 4; ++i)
#pragma unroll
        for (int j = 0; j < 8; ++j) { ak[i][j] = 0.f; av[i][j] = 0.f; }
    for (int kc = 0; kc < 128; kc += 32) {
        for (int s = tid; s < 2048; s += 256) {
            const int k = s >> 6, n = s & 63;
            float fv = 0.f;
            if (n0 + n < HWN)
                fv = feat[((size_t)b * 128 + kc + k) * HWN + n0 + n]
                   + kpeT[(size_t)(kc + k) * HWN + n0 + n];
            as[k][n] = fv;
        }
        for (int s = tid; s < 4096; s += 256) {
            const int k = s >> 7, c = s & 127;
            wk[k][c] = w[(128 + kc + k) * 128 + c];
            wv[k][c] = w[(256 + kc + k) * 128 + c];
        }
        __syncthreads();
#pragma unroll
        for (int k = 0; k < 32; ++k) {
            const float4 x0 = *(const float4*)&as[k][ng * 8];
            const float4 x1 = *(const float4*)&as[k][ng * 8 + 4];
            const float4 wk4 = *(const float4*)&wk[k][cg * 4];
            const float4 wv4 = *(const float4*)&wv[k][cg * 4];
            float xv[8] = {x0.x, x0.y, x0.z, x0.w, x1.x, x1.y, x1.z, x1.w};
#pragma unroll
            for (int j = 0; j < 8; ++j) {
                ak[0][j] += wk4.x * xv[j]; ak[1][j] += wk4.y * xv[j];
                ak[2][j] += wk4.z * xv[j]; ak[3][j] += wk4.w * xv[j];
                av[0][j] += wv4.x * xv[j]; av[1][j] += wv4.y * xv[j];
                av[2][j] += wv4.z * xv[j]; av[3][j] += wv4.w * xv[j];
            }
        }
        __syncthreads();
    }
    const float bk0 = bias[128 + cg * 4], bk1 = bias[128 + cg * 4 + 1];
    const float bk2 = bias[128 + cg * 4 + 2], bk3 = bias[128 + cg * 4 + 3];
    const float bv0 = bias[256 + cg * 4], bv1 = bias[256 + cg * 4 + 1];
    const float bv2 = bias[256 + cg * 4 + 2], bv3 = bias[256 + cg * 4 + 3];
#pragma unroll
    for (int j = 0; j < 8; ++j) {
        const int n = n0 + ng * 8 + j;
        if (n < HWN) {
            float4 ko = make_float4(ak[0][j] + bk0, ak[1][j] + bk1, ak[2][j] + bk2, ak[3][j] + bk3);
            float4 vo = make_float4(av[0][j] + bv0, av[1][j] + bv1, av[2][j] + bv2, av[3][j] + bv3);
            *(float4*)(kh + ((size_t)b * HWN + n) * 128 + cg * 4) = ko;
            *(float4*)(vh + ((size_t)b * HWN + n) * 128 + cg * 4) = vo;
        }
    }
}

// ---------------- flash cross-attention, split-K ------------------------------
#define KSPLIT 16
__global__ __launch_bounds__(256) void k_flash(const float* __restrict__ qh,
    const float* __restrict__ kh, const float* __restrict__ vh,
    float* __restrict__ o_part, float* __restrict__ m_part, float* __restrict__ l_part)
{
    __shared__ float ksm[64][16];
    __shared__ float vsm[64][16];
    const int bh = blockIdx.x, rt = blockIdx.y, ksid = blockIdx.z;
    const int b = bh >> 3, h = bh & 7;
    const int tid = threadIdx.x;
    const int wave = tid >> 6, lane = tid & 63;
    const int r2 = lane >> 2, qd = lane & 3;
    const int row0 = rt * 128 + wave * 32 + r2 * 2;
    float q0r[16], q1r[16];
    {
        const bool a0 = row0 < 200, a1 = row0 + 1 < 200;
#pragma unroll
        for (int d = 0; d < 16; ++d) {
            q0r[d] = a0 ? qh[((size_t)b * 200 + row0) * 128 + h * 16 + d] * 0.25f : 0.f;
            q1r[d] = a1 ? qh[((size_t)b * 200 + row0 + 1) * 128 + h * 16 + d] * 0.25f : 0.f;
        }
    }
    const int nBase = ksid * (HWN / KSPLIT), nEnd = nBase + (HWN / KSPLIT);
    float m0 = -1e30f, m1 = -1e30f, l0 = 0.f, l1 = 0.f;
    float acc0[16], acc1[16];
#pragma unroll
    for (int d = 0; d < 16; ++d) { acc0[d] = 0.f; acc1[d] = 0.f; }
    for (int c0 = nBase; c0 < nEnd; c0 += 64) {
        const int cnt = (nEnd - c0 < 64) ? (nEnd - c0) : 64;
        __syncthreads();
        {
            const int n = tid >> 2, d0 = (tid & 3) << 2;
            float4 kv = make_float4(0, 0, 0, 0), vv = make_float4(0, 0, 0, 0);
            if (n < cnt) {
                kv = *(const float4*)(kh + ((size_t)b * HWN + c0 + n) * 128 + h * 16 + d0);
                vv = *(const float4*)(vh + ((size_t)b * HWN + c0 + n) * 128 + h * 16 + d0);
            }
            *(float4*)(&ksm[n][d0]) = kv;
            *(float4*)(&vsm[n][d0]) = vv;
        }
        __syncthreads();
        float s0[16], s1[16];
        float cm0 = -1e30f, cm1 = -1e30f;
#pragma unroll
        for (int jj = 0; jj < 16; ++jj) {
            const int j = (jj << 2) | qd;
            float t0 = 0.f, t1 = 0.f;
#pragma unroll
            for (int d = 0; d < 16; ++d) {
                const float kvv = ksm[j][d];
                t0 += q0r[d] * kvv; t1 += q1r[d] * kvv;
            }
            const bool valid = j < cnt;
            t0 = valid ? t0 : -1e30f;
            t1 = valid ? t1 : -1e30f;
            s0[jj] = t0; s1[jj] = t1;
            cm0 = fmaxf(cm0, t0); cm1 = fmaxf(cm1, t1);
        }
        cm0 = fmaxf(cm0, __shfl_xor(cm0, 1)); cm0 = fmaxf(cm0, __shfl_xor(cm0, 2));
        cm1 = fmaxf(cm1, __shfl_xor(cm1, 1)); cm1 = fmaxf(cm1, __shfl_xor(cm1, 2));
        const float mn0 = fmaxf(m0, cm0), mn1 = fmaxf(m1, cm1);
        const float cr0 = __expf(m0 - mn0), cr1 = __expf(m1 - mn1);
        l0 *= cr0; l1 *= cr1;
#pragma unroll
        for (int d = 0; d < 16; ++d) { acc0[d] *= cr0; acc1[d] *= cr1; }
#pragma unroll
        for (int jj = 0; jj < 16; ++jj) {
            const int j = (jj << 2) | qd;
            const float p0 = __expf(s0[jj] - mn0);
            const float p1 = __expf(s1[jj] - mn1);
            l0 += p0; l1 += p1;
#pragma unroll
            for (int d = 0; d < 16; ++d) {
                const float vvv = vsm[j][d];
                acc0[d] += p0 * vvv; acc1[d] += p1 * vvv;
            }
        }
        m0 = mn0; m1 = mn1;
    }
    l0 += __shfl_xor(l0, 1); l0 += __shfl_xor(l0, 2);
    l1 += __shfl_xor(l1, 1); l1 += __shfl_xor(l1, 2);
#pragma unroll
    for (int d = 0; d < 16; ++d) {
        acc0[d] += __shfl_xor(acc0[d], 1); acc0[d] += __shfl_xor(acc0[d], 2);
        acc1[d] += __shfl_xor(acc1[d], 1); acc1[d] += __shfl_xor(acc1[d], 2);
    }
    if (qd == 0) {
        const size_t pbase = ((size_t)bh * KSPLIT + ksid) * 200;
        if (row0 < 200) {
#pragma unroll
            for (int d = 0; d < 16; ++d) o_part[(pbase + row0) * 16 + d] = acc0[d];
            m_part[pbase + row0] = m0; l_part[pbase + row0] = l0;
        }
        if (row0 + 1 < 200) {
#pragma unroll
            for (int d = 0; d < 16; ++d) o_part[(pbase + row0 + 1) * 16 + d] = acc1[d];
            m_part[pbase + row0 + 1] = m1; l_part[pbase + row0 + 1] = l1;
        }
    }
}

// ---------------- merge flash splits ------------------------------------------
__global__ __launch_bounds__(64) void k_merge(const float* __restrict__ o_part,
    const float* __restrict__ m_part, const float* __restrict__ l_part,
    float* __restrict__ o_c)
{
    const int row = blockIdx.x, bh = blockIdx.y;
    const int b = bh >> 3, h = bh & 7;
    const int lane = threadIdx.x;
    float M = -1e30f;
#pragma unroll
    for (int k = 0; k < KSPLIT; ++k)
        M = fmaxf(M, m_part[((size_t)bh * KSPLIT + k) * 200 + row]);
    float L = 0.f;
#pragma unroll
    for (int k = 0; k < KSPLIT; ++k)
        L += l_part[((size_t)bh * KSPLIT + k) * 200 + row]
           * __expf(m_part[((size_t)bh * KSPLIT + k) * 200 + row] - M);
    if (lane < 16) {
        float o = 0.f;
#pragma unroll
        for (int k = 0; k < KSPLIT; ++k)
            o += o_part[(((size_t)bh * KSPLIT + k) * 200 + row) * 16 + lane]
               * __expf(m_part[((size_t)bh * KSPLIT + k) * 200 + row] - M);
        o_c[((size_t)b * 200 + row) * 128 + h * 16 + lane] = o / L;
    }
}

// ---------------- FFN + residual + LN3 ----------------------------------------
__global__ __launch_bounds__(256) void k_ffn_ln(const float* __restrict__ x,
    const float* __restrict__ w1, const float* __restrict__ b1,
    const float* __restrict__ w2, const float* __restrict__ b2,
    const float* __restrict__ g, const float* __restrict__ lb, float* __restrict__ out)
{
    __shared__ float xr[128];
    __shared__ float hs[256];
    __shared__ float rbuf[8];
    const int p = blockIdx.x, b = blockIdx.y, t = threadIdx.x;
    const size_t base = ((size_t)b * 200 + p) * 128;
    if (t < 128) xr[t] = x[base + t];
    __syncthreads();
    float hv = b1[t];
    for (int k = 0; k < 128; ++k) hv += xr[k] * w1[k * 256 + t];
    hs[t] = fmaxf(hv, 0.f);
    __syncthreads();
    float v = 0.f;
    if (t < 128) {
        v = b2[t] + xr[t];
        for (int k = 0; k < 256; ++k) v += hs[k] * w2[k * 128 + t];
    }
    float s = (t < 128) ? v : 0.f;
#pragma unroll
    for (int off = 32; off >= 1; off >>= 1) s += __shfl_xor(s, off);
    if ((t & 63) == 0) rbuf[t >> 6] = s;
    __syncthreads();
    const float mean = (rbuf[0] + rbuf[1] + rbuf[2] + rbuf[3]) * (1.f / 128.f);
    const float dv = v - mean;
    float s2 = (t < 128) ? dv * dv : 0.f;
#pragma unroll
    for (int off = 32; off >= 1; off >>= 1) s2 += __shfl_xor(s2, off);
    if ((t & 63) == 0) rbuf[4 + (t >> 6)] = s2;
    __syncthreads();
    const float var = (rbuf[4] + rbuf[5] + rbuf[6] + rbuf[7]) * (1.f / 128.f);
    if (t < 128) out[base + t] = g[t] * dv / sqrtf(var + 1e-5f) + lb[t];
}

// ---------------- separate heads: conv1 + BN + ReLU ---------------------------
__global__ __launch_bounds__(256) void k_head_h(const float* __restrict__ q3,
    const float* __restrict__ w1, const float* __restrict__ b1,
    const float* __restrict__ g, const float* __restrict__ beta,
    float* __restrict__ h_all)
{
    __shared__ float qw[128][32];
    const int pt = blockIdx.x, ih = blockIdx.y, b = blockIdx.z;
    const int tid = threadIdx.x;
    for (int s = tid; s < 4096; s += 256) {
        const int c = s & 127, wg = s >> 7;
        const int pg = pt * 24 - 1 + wg;
        qw[c][wg] = ((unsigned)pg < 200u) ? q3[((size_t)b * 200 + pg) * 128 + c] : 0.f;
    }
    __syncthreads();
    const int c = tid & 127, half = tid >> 7;
    float acc[12];
#pragma unroll
    for (int pp = 0; pp < 12; ++pp) acc[pp] = 0.f;
    const float* wbase = w1 + ((size_t)ih * 128 + c) * 384;
    for (int cin = 0; cin < 128; ++cin) {
        const float4* qp = (const float4*)&qw[cin][half * 12];
        const float4 a0 = qp[0], a1 = qp[1], a2 = qp[2], a3 = qp[3];
        float xr[16] = {a0.x, a0.y, a0.z, a0.w, a1.x, a1.y, a1.z, a1.w,
                        a2.x, a2.y, a2.z, a2.w, a3.x, a3.y, a3.z, a3.w};
        const float w0 = wbase[cin * 3], w1v = wbase[cin * 3 + 1], w2v = wbase[cin * 3 + 2];
#pragma unroll
        for (int pp = 0; pp < 12; ++pp)
            acc[pp] += xr[pp] * w0 + xr[pp + 1] * w1v + xr[pp + 2] * w2v;
    }
    const float bs = b1[ih * 128 + c], gg = g[ih * 128 + c], bt = beta[ih * 128 + c];
#pragma unroll
    for (int pp = 0; pp < 12; ++pp) {
        const int p = pt * 24 + half * 12 + pp;
        if (p < 200)
            h_all[(((size_t)b * 6 + ih) * 128 + c) * 200 + p] =
                fmaxf(gg * (acc[pp] + bs) + bt, 0.f);
    }
}

// ---------------- separate heads: conv2 + hm-score fusion ---------------------
__global__ void k_head_out(const float* __restrict__ h_all, const float* __restrict__ w2,
    const float* __restrict__ b2, const float* __restrict__ qhm, float* __restrict__ out)
{
    const int gid = blockIdx.x * 256 + threadIdx.x;
    if (gid >= 8000) return;
    const int p = gid % 200, rem = gid / 200, row = rem % 20, b = rem / 20;
    int i, oo;
    if (row < 2)       { i = 0; oo = row; }
    else if (row < 3)  { i = 1; oo = row - 2; }
    else if (row < 6)  { i = 2; oo = row - 3; }
    else if (row < 8)  { i = 3; oo = row - 6; }
    else if (row < 10) { i = 4; oo = row - 8; }
    else               { i = 5; oo = row - 10; }
    const float* hb = h_all + (((size_t)b * 6 + i) * 128) * 200;
    const float* wb = w2 + ((size_t)i * 10 + oo) * 384;
    float acc = b2[i * 10 + oo];
    for (int c = 0; c < 128; ++c) {
        const float* hr = hb + (size_t)c * 200 + p;
        const float x0 = (p > 0) ? hr[-1] : 0.f;
        const float x1 = hr[0];
        const float x2 = (p < 199) ? hr[1] : 0.f;
        acc += x0 * wb[c * 3] + x1 * wb[c * 3 + 1] + x2 * wb[c * 3 + 2];
    }
    if (i == 5) acc += qhm[((size_t)b * 10 + oo) * 200 + p];
    out[((size_t)b * 20 + row) * 200 + p] = acc;
}

// ---------------- launcher ----------------------------------------------------
extern "C" void kernel_launch(void* const* d_in, const int* in_sizes, int n_in,
                              void* d_out, int out_size, void* d_ws, size_t ws_size,
                              hipStream_t stream) {
    (void)in_sizes; (void)n_in; (void)out_size; (void)ws_size;
    const float* x        = (const float*)d_in[0];
    const float* w_shared = (const float*)d_in[1];
    const float* b_shared = (const float*)d_in[2];
    const float* w_hm1    = (const float*)d_in[3];
    const float* b_hm1    = (const float*)d_in[4];
    const float* g_hm1    = (const float*)d_in[5];
    const float* beta_hm1 = (const float*)d_in[6];
    const float* w_hm2    = (const float*)d_in[7];
    const float* b_hm2    = (const float*)d_in[8];
    const float* w_be1    = (const float*)d_in[15];
    const float* b_be1    = (const float*)d_in[16];
    const float* w_be2    = (const float*)d_in[17];
    const float* b_be2    = (const float*)d_in[18];
    const float* w_attn_s = (const float*)d_in[19];
    const float* b_attn_s = (const float*)d_in[20];
    const float* w_out_s  = (const float*)d_in[21];
    const float* b_out_s  = (const float*)d_in[22];
    const float* w_attn_c = (const float*)d_in[23];
    const float* b_attn_c = (const float*)d_in[24];
    const float* w_out_c  = (const float*)d_in[25];
    const float* b_out_c  = (const float*)d_in[26];
    const float* ln1_g    = (const float*)d_in[27];
    const float* ln1_b    = (const float*)d_in[28];
    const float* ln2_g    = (const float*)d_in[29];
    const float* ln2_b    = (const float*)d_in[30];
    const float* ln3_g    = (const float*)d_in[31];
    const float* ln3_b    = (const float*)d_in[32];
    const float* w_ff1    = (const float*)d_in[33];
    const float* b_ff1    = (const float*)d_in[34];
    const float* w_ff2    = (const float*)d_in[35];
    const float* b_ff2    = (const float*)d_in[36];
    const float* w_head1  = (const float*)d_in[37];
    const float* b_head1  = (const float*)d_in[38];
    const float* g_head1  = (const float*)d_in[39];
    const float* bt_head1 = (const float*)d_in[40];
    const float* w_head2  = (const float*)d_in[41];
    const float* b_head2  = (const float*)d_in[42];

    char* ws = (char*)d_ws;
    size_t off = 0;
    auto alloc = [&](size_t bytes) { size_t o = off; off += (bytes + 255) & ~(size_t)255; return o; };
    float* wt_s   = (float*)(ws + alloc((size_t)9*384*128*4));
    float* wt_h1  = (float*)(ws + alloc((size_t)9*128*128*4));
    float* feat   = (float*)(ws + alloc((size_t)2*128*HWN*4));
    float* bufA   = (float*)(ws + alloc((size_t)2*128*HWN*4));  // h1, later kh_c
    float* bufB   = (float*)(ws + alloc((size_t)2*128*HWN*4));  // vh_c
    float* hm_raw = (float*)(ws + alloc((size_t)2*10*HWN*4));
    float* hm_msk = (float*)(ws + alloc((size_t)2*10*HWN*4));
    float* kpeT   = (float*)(ws + alloc((size_t)128*HWN*4));
    int*   topidx = (int*)  (ws + alloc((size_t)2*200*4));
    float* q0     = (float*)(ws + alloc((size_t)2*200*128*4));
    float* qpe    = (float*)(ws + alloc((size_t)2*200*128*4));
    float* q_hm   = (float*)(ws + alloc((size_t)2*10*200*4));
    float* qh_s   = (float*)(ws + alloc((size_t)2*200*128*4));
    float* kh_s   = (float*)(ws + alloc((size_t)2*200*128*4));
    float* vh_s   = (float*)(ws + alloc((size_t)2*200*128*4));
    float* o_s    = (float*)(ws + alloc((size_t)2*200*128*4));
    float* q1n    = (float*)(ws + alloc((size_t)2*200*128*4));
    float* qh_c   = (float*)(ws + alloc((size_t)2*200*128*4));
    float* o_part = (float*)(ws + alloc((size_t)16*KSPLIT*200*16*4));
    float* m_part = (float*)(ws + alloc((size_t)16*KSPLIT*200*4));
    float* l_part = (float*)(ws + alloc((size_t)16*KSPLIT*200*4));
    float* o_c    = (float*)(ws + alloc((size_t)2*200*128*4));
    float* q2n    = (float*)(ws + alloc((size_t)2*200*128*4));
    float* q3     = (float*)(ws + alloc((size_t)2*200*128*4));
    float* h_all  = (float*)(ws + alloc((size_t)2*6*128*200*4));

    k_transw<<<(9*384*128 + 255)/256, 256, 0, stream>>>(w_shared, wt_s, 384);
    k_transw<<<(9*128*128 + 255)/256, 256, 0, stream>>>(w_hm1, wt_h1, 128);
    k_kpe<<<HWN/8, 128, 0, stream>>>(w_be1, b_be1, w_be2, b_be2, kpeT);
    k_conv3x3<384, 0><<<dim3(3, 180, 2), 128, 0, stream>>>(x, wt_s, b_shared, nullptr, nullptr, feat);
    k_conv3x3<128, 1><<<dim3(3, 180, 2), 128, 0, stream>>>(feat, wt_h1, b_hm1, g_hm1, beta_hm1, bufA);
    k_convhm2<<<dim3(180, 2), 192, 0, stream>>>(bufA, w_hm2, b_hm2, hm_raw);
    k_nms<<<(2*10*HWN + 255)/256, 256, 0, stream>>>(hm_raw, hm_msk);
    k_topk<<<2, 1024, 0, stream>>>(hm_msk, topidx);
    k_gather<<<dim3(200, 2), 128, 0, stream>>>(feat, kpeT, hm_msk, topidx, q0, qpe, q_hm);
    k_proj_self<<<dim3(200, 2), 128, 0, stream>>>(q0, qpe, w_attn_s, b_attn_s, qh_s, kh_s, vh_s);
    k_attn_self<<<dim3(8, 2), 256, 0, stream>>>(qh_s, kh_s, vh_s, o_s);
    k_proj_ln<<<dim3(200, 2), 128, 0, stream>>>(o_s, w_out_s, b_out_s, q0, ln1_g, ln1_b, q1n);
    k_proj_q<<<dim3(200, 2), 128, 0, stream>>>(q1n, qpe, w_attn_c, b_attn_c, qh_c);
    k_kv_cross<<<dim3(507, 2), 256, 0, stream>>>(feat, kpeT, w_attn_c, b_attn_c, bufA, bufB);
    k_flash<<<dim3(16, 2, KSPLIT), 256, 0, stream>>>(qh_c, bufA, bufB, o_part, m_part, l_part);
    k_merge<<<dim3(200, 16), 64, 0, stream>>>(o_part, m_part, l_part, o_c);
    k_proj_ln<<<dim3(200, 2), 128, 0, stream>>>(o_c, w_out_c, b_out_c, q1n, ln2_g, ln2_b, q2n);
    k_ffn_ln<<<dim3(200, 2), 256, 0, stream>>>(q2n, w_ff1, b_ff1, w_ff2, b_ff2, ln3_g, ln3_b, q3);
    k_head_h<<<dim3(9, 6, 2), 256, 0, stream>>>(q3, w_head1, b_head1, g_head1, bt_head1, h_all);
    k_head_out<<<32, 256, 0, stream>>>(h_all, w_head2, b_head2, q_hm, (float*)d_out);
}

// Round 3
// 1684.156 us; speedup vs baseline: 1.6741x; 1.6741x over previous
//
#include <hip/hip_runtime.h>

#define HH 180
#define WW 180
#define HWN 32400
#define CC 128
#define CINN 384
#define KK 10
#define PP 200
#define NHH 8
#define BB 2
#define NTOT 324000  // K*H*W per batch

typedef _Float16 half8 __attribute__((ext_vector_type(8)));
typedef float f32x16 __attribute__((ext_vector_type(16)));

static __device__ __forceinline__ f32x16 MFMA16(half8 a, half8 b, f32x16 c) {
    return __builtin_amdgcn_mfma_f32_32x32x16_f16(a, b, c, 0, 0, 0);
}

// ------ weight split+image: img[(ch*9+tap)][term][cout*32+slot] fp16 ----------
// slot = pblk*8+i holds cin-block blk = pblk ^ ((cout>>1)&3)  (swizzle pre-baked)
__global__ void k_wsplit(const float* __restrict__ w, _Float16* __restrict__ img, int cint) {
    const int idx = blockIdx.x * 256 + threadIdx.x;
    const int total = (cint / 32) * 9 * 128 * 32;
    if (idx >= total) return;
    const int slot = idx & 31;
    const int cout = (idx >> 5) & 127;
    const int tap  = (idx >> 12) % 9;
    const int ch   = (idx >> 12) / 9;
    const int pblk = slot >> 3, ii = slot & 7;
    const int blk  = pblk ^ ((cout >> 1) & 3);
    const int cin  = ch * 32 + blk * 8 + ii;
    const float v  = w[((size_t)cout * cint + cin) * 9 + tap];
    const _Float16 h  = (_Float16)v;
    const _Float16 ls = (_Float16)((v - (float)h) * 256.f);
    const size_t base = ((size_t)(ch * 9 + tap) * 2) * 4096 + cout * 32 + slot;
    img[base] = h;
    img[base + 4096] = ls;
}

// ------ MFMA 3x3 conv via fp16 two-term split (fp32-grade accuracy) -----------
// block: 128 cout x (2 rows x 64 px), 4 waves (2x2), cin-chunk 32, 9 taps.
template<int CINT, int EPI>
__global__ __launch_bounds__(256, 2) void k_conv_mfma(
    const float* __restrict__ x, const _Float16* __restrict__ wimg,
    const float* __restrict__ bias, const float* __restrict__ g,
    const float* __restrict__ beta, float* __restrict__ out)
{
    constexpr int NCH = CINT / 32;
    __shared__ __align__(16) char sh[67584];
    _Float16* A = (_Float16*)sh;                    // [2 term][4 row][66][32]
    const int tid = threadIdx.x;
    const int b = blockIdx.z, oy0 = blockIdx.y * 2, ox0 = blockIdx.x * 64;
    const int wave = tid >> 6, l = tid & 63;
    const int wm = wave >> 1, wn = wave & 1;
    const int r = l & 31, kb = l >> 5;

    int i32off[2][3], aswz[2][3];
#pragma unroll
    for (int mf = 0; mf < 2; ++mf)
#pragma unroll
        for (int kx = 0; kx < 3; ++kx) {
            const int i = mf * 32 + r + kx;
            i32off[mf][kx] = i * 32;
            aswz[mf][kx] = (i >> 1) & 3;
        }
    int bbase[2], bswz[2];
#pragma unroll
    for (int nf = 0; nf < 2; ++nf) {
        const int co = wn * 64 + nf * 32 + r;
        bbase[nf] = co * 32;
        bswz[nf] = (co >> 1) & 3;
    }

    auto stageA = [&](int ch) {
        const int c0 = ch * 32;
        const int combo = tid >> 1, hf = tid & 1;
        const int ci = combo & 31, rr = combo >> 5;
        const int gy = oy0 - 1 + rr;
        const bool rowok = (unsigned)gy < (unsigned)HH;
        const float* xrow = x + ((size_t)(b * CINT + c0 + ci) * HH + (rowok ? gy : 0)) * WW;
        const int sb = ci & 7, blkci = ci >> 3;
        for (int ii = 0; ii < 33; ++ii) {
            const int i = hf * 33 + ii;
            const int gx = ox0 - 1 + i;
            float v = 0.f;
            if (rowok && (unsigned)gx < (unsigned)WW) v = xrow[gx];
            const _Float16 h = (_Float16)v;
            const _Float16 ls = (_Float16)((v - (float)h) * 256.f);
            const int base = (rr * 66 + i) * 32 + ((blkci ^ ((i >> 1) & 3)) << 3) + sb;
            A[base] = h;
            A[8448 + base] = ls;
        }
    };

    f32x16 acc1[2][2] = {};
    f32x16 acc2[2][2] = {};

    stageA(0);
    {
        const uint4* s4 = (const uint4*)wimg;
        uint4* d4 = (uint4*)(sh + 33792);
        d4[tid] = s4[tid]; d4[tid + 256] = s4[tid + 256];
        d4[tid + 512] = s4[tid + 512]; d4[tid + 768] = s4[tid + 768];
    }
    __syncthreads();

    int buf = 0;
    for (int ch = 0; ch < NCH; ++ch) {
        for (int tap = 0; tap < 9; ++tap) {
            const int bidx = ch * 9 + tap;
            const int ky = tap / 3, kx = tap % 3;
            uint4 p0, p1, p2, p3;
            const bool pf = (bidx + 1 < NCH * 9);
            if (pf) {  // issue-early (T14): prefetch next tap's weight image
                const uint4* s4 = (const uint4*)wimg + (size_t)(bidx + 1) * 1024;
                p0 = s4[tid]; p1 = s4[tid + 256]; p2 = s4[tid + 512]; p3 = s4[tid + 768];
            }
            const _Float16* B = (const _Float16*)(sh + 33792 + buf * 16384);
            const int rowoff = (wm + ky) * 2112;
#pragma unroll
            for (int s = 0; s < 2; ++s) {
                const int s2kb = s * 2 + kb;
                half8 ah[2], al[2], bh[2], bl[2];
#pragma unroll
                for (int mf = 0; mf < 2; ++mf) {
                    const int o = rowoff + i32off[mf][kx] + ((s2kb ^ aswz[mf][kx]) << 3);
                    ah[mf] = *(const half8*)(A + o);
                    al[mf] = *(const half8*)(A + 8448 + o);
                }
#pragma unroll
                for (int nf = 0; nf < 2; ++nf) {
                    const int o = bbase[nf] + ((s2kb ^ bswz[nf]) << 3);
                    bh[nf] = *(const half8*)(B + o);
                    bl[nf] = *(const half8*)(B + 4096 + o);
                }
#pragma unroll
                for (int mf = 0; mf < 2; ++mf)
#pragma unroll
                    for (int nf = 0; nf < 2; ++nf) {
                        acc1[mf][nf] = MFMA16(ah[mf], bh[nf], acc1[mf][nf]);
                        acc2[mf][nf] = MFMA16(ah[mf], bl[nf], acc2[mf][nf]);
                        acc2[mf][nf] = MFMA16(al[mf], bh[nf], acc2[mf][nf]);
                    }
            }
            if (pf) {  // write-late into the other buffer
                uint4* d4 = (uint4*)(sh + 33792 + (buf ^ 1) * 16384);
                d4[tid] = p0; d4[tid + 256] = p1; d4[tid + 512] = p2; d4[tid + 768] = p3;
            }
            __syncthreads();
            if (tap == 8 && ch + 1 < NCH) { stageA(ch + 1); __syncthreads(); }
            buf ^= 1;
        }
    }

    // epilogue: acc -> padded LDS tile -> coalesced float4 stores
    float* C = (float*)sh;
#pragma unroll
    for (int mf = 0; mf < 2; ++mf)
#pragma unroll
        for (int nf = 0; nf < 2; ++nf) {
#pragma unroll
            for (int reg = 0; reg < 16; ++reg) {
                const int row = (reg & 3) + 8 * (reg >> 2) + 4 * kb;
                const int pxl = mf * 32 + row;
                C[(wn * 64 + nf * 32 + r) * 132 + wm * 64 + pxl] =
                    acc1[mf][nf][reg] + acc2[mf][nf][reg] * (1.f / 256.f);
            }
        }
    __syncthreads();
    for (int s = tid; s < 4096; s += 256) {
        const int cout = s >> 5, rem = s & 31, row = rem >> 4, px = (rem & 15) * 4;
        const int gx = ox0 + px;
        if (gx < WW) {
            float4 v = *(const float4*)(C + cout * 132 + row * 64 + px);
            const float bv = bias[cout];
            v.x += bv; v.y += bv; v.z += bv; v.w += bv;
            if constexpr (EPI) {
                const float gg = g[cout], bb = beta[cout];
                v.x = fmaxf(gg * v.x + bb, 0.f); v.y = fmaxf(gg * v.y + bb, 0.f);
                v.z = fmaxf(gg * v.z + bb, 0.f); v.w = fmaxf(gg * v.w + bb, 0.f);
            }
            *(float4*)(out + ((size_t)(b * 128 + cout) * HH + (oy0 + row)) * WW + gx) = v;
        }
    }
}

// ---------------- heatmap conv2 (128->10) + sigmoid ---------------------------
__global__ __launch_bounds__(192) void k_convhm2(const float* __restrict__ h1,
    const float* __restrict__ w, const float* __restrict__ bias,
    float* __restrict__ hm_raw)
{
    __shared__ float xs[8][3][184];
    __shared__ float ws[11520];
    const int tid = threadIdx.x, oy = blockIdx.x, b = blockIdx.y;
    for (int s = tid; s < 11520; s += 192) ws[s] = w[s];
    float acc[10];
#pragma unroll
    for (int o = 0; o < 10; ++o) acc[o] = 0.f;
    for (int c0 = 0; c0 < 128; c0 += 8) {
        __syncthreads();
        for (int s = tid; s < 4368; s += 192) {
            int c = s / 546, rem = s % 546, r = rem / 182, i = rem % 182;
            int row = oy + r - 1, px = i - 1;
            float v = 0.f;
            if ((unsigned)row < (unsigned)HH && (unsigned)px < (unsigned)WW)
                v = h1[(((size_t)b * 128 + c0 + c) * HH + row) * WW + px];
            xs[c][r][i] = v;
        }
        __syncthreads();
        if (tid < 180) {
#pragma unroll
            for (int c = 0; c < 8; ++c) {
#pragma unroll
                for (int ky = 0; ky < 3; ++ky) {
                    const float x0 = xs[c][ky][tid];
                    const float x1 = xs[c][ky][tid + 1];
                    const float x2 = xs[c][ky][tid + 2];
#pragma unroll
                    for (int o = 0; o < 10; ++o) {
                        const float* wp = &ws[((size_t)o * 128 + c0 + c) * 9 + ky * 3];
                        acc[o] += x0 * wp[0] + x1 * wp[1] + x2 * wp[2];
                    }
                }
            }
        }
    }
    if (tid < 180) {
#pragma unroll
        for (int o = 0; o < 10; ++o) {
            const float z = acc[o] + bias[o];
            hm_raw[(((size_t)b * 10 + o) * HH + oy) * WW + tid] = 1.f / (1.f + expf(-z));
        }
    }
}

// ---------------- 3x3 local-max NMS mask --------------------------------------
__global__ void k_nms(const float* __restrict__ hm, float* __restrict__ out) {
    int i = blockIdx.x * 256 + threadIdx.x;
    if (i >= BB * KK * HWN) return;
    int xx = i % WW, yy = (i / WW) % HH, ck = i / HWN;
    float v = hm[i], m = v;
    for (int dy = -1; dy <= 1; ++dy) {
        int ny = yy + dy;
        if ((unsigned)ny >= (unsigned)HH) continue;
        for (int dx = -1; dx <= 1; ++dx) {
            int nx = xx + dx;
            if ((unsigned)nx >= (unsigned)WW) continue;
            m = fmaxf(m, hm[(size_t)ck * HWN + ny * WW + nx]);
        }
    }
    out[i] = (v == m) ? v : 0.f;
}

// ---------------- exact top-200 (radix select + bitonic sort) -----------------
__global__ __launch_bounds__(1024) void k_topk(const float* __restrict__ hm_msk,
                                               int* __restrict__ top_idx) {
    const int b = blockIdx.x, tid = threadIdx.x;
    const float* src = hm_msk + (size_t)b * NTOT;
    __shared__ unsigned hist[256];
    __shared__ unsigned sh_prefix, sh_rem, sh_cnt;
    __shared__ unsigned long long buf[1024];
    if (tid == 0) { sh_prefix = 0u; sh_rem = 200u; sh_cnt = 0u; }
    __syncthreads();
    for (int r = 3; r >= 0; --r) {
        if (tid < 256) hist[tid] = 0u;
        __syncthreads();
        const unsigned pfx = sh_prefix;
        for (int i = tid; i < NTOT; i += 1024) {
            const unsigned key = __float_as_uint(src[i]);
            const bool ok = (r == 3) || ((key >> ((r + 1) * 8)) == pfx);
            if (ok) atomicAdd(&hist[(key >> (r * 8)) & 255u], 1u);
        }
        __syncthreads();
        if (tid == 0) {
            unsigned acc = 0, rem = sh_rem;
            int v;
            for (v = 255; v >= 0; --v) {
                const unsigned h = hist[v];
                if (acc + h >= rem) break;
                acc += h;
            }
            if (v < 0) v = 0;  // safety (cannot happen)
            sh_prefix = (pfx << 8) | (unsigned)v;
            sh_rem = rem - acc;
        }
        __syncthreads();
    }
    const unsigned pivot = sh_prefix;
    for (int i = tid; i < NTOT; i += 1024) {
        const unsigned key = __float_as_uint(src[i]);
        if (key >= pivot) {
            const unsigned pos = atomicAdd(&sh_cnt, 1u);
            if (pos < 1024u)
                buf[pos] = (((unsigned long long)(~key)) << 32) | (unsigned)i;
        }
    }
    __syncthreads();
    const unsigned cnt = sh_cnt < 1024u ? sh_cnt : 1024u;
    if ((unsigned)tid >= cnt) buf[tid] = 0xFFFFFFFFFFFFFFFFull;
    __syncthreads();
    for (int k = 2; k <= 1024; k <<= 1) {
        for (int j = k >> 1; j > 0; j >>= 1) {
            const int ixj = tid ^ j;
            if (ixj > tid) {
                const unsigned long long a = buf[tid], c = buf[ixj];
                const bool up = ((tid & k) == 0);
                if ((a > c) == up) { buf[tid] = c; buf[ixj] = a; }
            }
            __syncthreads();
        }
    }
    if (tid < 200) {
        const int idx = (int)(buf[tid] & 0xFFFFFFFFull);
        top_idx[b * 200 + tid] = idx % HWN;
    }
}

// ---------------- kpe for all BEV positions (stored transposed [128][HW]) -----
__global__ __launch_bounds__(128) void k_kpe(const float* __restrict__ w1,
    const float* __restrict__ b1, const float* __restrict__ w2,
    const float* __restrict__ b2, float* __restrict__ kpeT)
{
    __shared__ float pe[8][258];
    __shared__ float hid[8][130];
    const int tid = threadIdx.x;
    const int pos0 = blockIdx.x * 8;
    const int half = tid >> 6, m = tid & 63;
    const float dimt = 1.f + (float)m * 0.015625f;
#pragma unroll
    for (int p = 0; p < 8; ++p) {
        const int pos = pos0 + p;
        const int i = pos / WW, j = pos % WW;
        const float coord = (half == 0) ? ((float)j + 0.5f) * (1.f / 180.f)
                                        : ((float)i + 0.5f) * (1.f / 180.f);
        const float arg = (coord * 6.2831855f) / dimt;
        pe[p][half * 128 + 2 * m]     = sinf(arg);
        pe[p][half * 128 + 2 * m + 1] = cosf(arg);
    }
    __syncthreads();
    float acc[8];
#pragma unroll
    for (int p = 0; p < 8; ++p) acc[p] = b1[tid];
    for (int k = 0; k < 256; ++k) {
        const float w = w1[k * 128 + tid];
#pragma unroll
        for (int p = 0; p < 8; ++p) acc[p] += pe[p][k] * w;
    }
#pragma unroll
    for (int p = 0; p < 8; ++p) hid[p][tid] = fmaxf(acc[p], 0.f);
    __syncthreads();
#pragma unroll
    for (int p = 0; p < 8; ++p) acc[p] = b2[tid];
    for (int k = 0; k < 128; ++k) {
        const float w = w2[k * 128 + tid];
#pragma unroll
        for (int p = 0; p < 8; ++p) acc[p] += hid[p][k] * w;
    }
#pragma unroll
    for (int p = 0; p < 8; ++p) kpeT[(size_t)tid * HWN + pos0 + p] = acc[p];
}

// ---------------- gather q0/qpe/q_hm ------------------------------------------
__global__ __launch_bounds__(128) void k_gather(const float* __restrict__ feat,
    const float* __restrict__ kpeT, const float* __restrict__ hm_msk,
    const int* __restrict__ top_idx, float* __restrict__ q0,
    float* __restrict__ qpe, float* __restrict__ qhm)
{
    const int p = blockIdx.x, b = blockIdx.y, c = threadIdx.x;
    const int idx = top_idx[b * 200 + p];
    q0[((size_t)b * 200 + p) * 128 + c]  = feat[((size_t)b * 128 + c) * HWN + idx];
    qpe[((size_t)b * 200 + p) * 128 + c] = kpeT[(size_t)c * HWN + idx];
    if (c < 10)
        qhm[((size_t)b * 10 + c) * 200 + p] = hm_msk[((size_t)b * 10 + c) * HWN + idx];
}

// ---------------- self-attn qkv projection ------------------------------------
__global__ __launch_bounds__(128) void k_proj_self(const float* __restrict__ q0,
    const float* __restrict__ qpe, const float* __restrict__ w,
    const float* __restrict__ bias, float* __restrict__ qh,
    float* __restrict__ kh, float* __restrict__ vh)
{
    __shared__ float in0[128], in1[128];
    const int p = blockIdx.x, b = blockIdx.y, c = threadIdx.x;
    const size_t base = ((size_t)b * 200 + p) * 128;
    const float a = q0[base + c], pe = qpe[base + c];
    in0[c] = a + pe; in1[c] = a;
    __syncthreads();
    float aq = bias[c], ak = bias[128 + c], av = bias[256 + c];
    for (int k = 0; k < 128; ++k) {
        const float i0 = in0[k];
        aq += i0 * w[k * 128 + c];
        ak += i0 * w[16384 + k * 128 + c];
        av += in1[k] * w[32768 + k * 128 + c];
    }
    qh[base + c] = aq; kh[base + c] = ak; vh[base + c] = av;
}

// ---------------- self-attention (200 keys) -----------------------------------
__global__ __launch_bounds__(256) void k_attn_self(const float* __restrict__ qh,
    const float* __restrict__ kh, const float* __restrict__ vh, float* __restrict__ o)
{
    __shared__ float ks[200][16], vs[200][16];
    const int h = blockIdx.x, b = blockIdx.y, tid = threadIdx.x;
    for (int s = tid; s < 3200; s += 256) {
        const int n = s >> 4, d = s & 15;
        ks[n][d] = kh[((size_t)b * 200 + n) * 128 + h * 16 + d];
        vs[n][d] = vh[((size_t)b * 200 + n) * 128 + h * 16 + d];
    }
    __syncthreads();
    if (tid < 200) {
        float q[16];
#pragma unroll
        for (int d = 0; d < 16; ++d)
            q[d] = qh[((size_t)b * 200 + tid) * 128 + h * 16 + d] * 0.25f;
        float mmax = -1e30f, l = 0.f, acc[16];
#pragma unroll
        for (int d = 0; d < 16; ++d) acc[d] = 0.f;
        for (int j = 0; j < 200; ++j) {
            float s = 0.f;
#pragma unroll
            for (int d = 0; d < 16; ++d) s += q[d] * ks[j][d];
            const float mn = fmaxf(mmax, s);
            const float corr = __expf(mmax - mn);
            const float pv = __expf(s - mn);
            l = l * corr + pv;
#pragma unroll
            for (int d = 0; d < 16; ++d) acc[d] = acc[d] * corr + pv * vs[j][d];
            mmax = mn;
        }
#pragma unroll
        for (int d = 0; d < 16; ++d)
            o[((size_t)b * 200 + tid) * 128 + h * 16 + d] = acc[d] / l;
    }
}

// ---------------- out-projection + residual + LayerNorm -----------------------
__global__ __launch_bounds__(128) void k_proj_ln(const float* __restrict__ src,
    const float* __restrict__ W, const float* __restrict__ bW,
    const float* __restrict__ resid, const float* __restrict__ g,
    const float* __restrict__ lb, float* __restrict__ out)
{
    __shared__ float sIn[128];
    __shared__ float rbuf[4];
    const int p = blockIdx.x, b = blockIdx.y, c = threadIdx.x;
    const size_t base = ((size_t)b * 200 + p) * 128;
    sIn[c] = src[base + c];
    __syncthreads();
    float v = bW[c] + resid[base + c];
    for (int k = 0; k < 128; ++k) v += sIn[k] * W[k * 128 + c];
    float s = v;
#pragma unroll
    for (int off = 32; off >= 1; off >>= 1) s += __shfl_xor(s, off);
    if ((c & 63) == 0) rbuf[c >> 6] = s;
    __syncthreads();
    const float mean = (rbuf[0] + rbuf[1]) * (1.f / 128.f);
    const float dv = v - mean;
    float s2 = dv * dv;
#pragma unroll
    for (int off = 32; off >= 1; off >>= 1) s2 += __shfl_xor(s2, off);
    if ((c & 63) == 0) rbuf[2 + (c >> 6)] = s2;
    __syncthreads();
    const float var = (rbuf[2] + rbuf[3]) * (1.f / 128.f);
    out[base + c] = g[c] * dv / sqrtf(var + 1e-5f) + lb[c];
}

// ---------------- cross-attn query projection ---------------------------------
__global__ __launch_bounds__(128) void k_proj_q(const float* __restrict__ q1n,
    const float* __restrict__ qpe, const float* __restrict__ w,
    const float* __restrict__ bw, float* __restrict__ out)
{
    __shared__ float in0[128];
    const int p = blockIdx.x, b = blockIdx.y, c = threadIdx.x;
    const size_t base = ((size_t)b * 200 + p) * 128;
    in0[c] = q1n[base + c] + qpe[base + c];
    __syncthreads();
    float a = bw[c];
    for (int k = 0; k < 128; ++k) a += in0[k] * w[k * 128 + c];
    out[base + c] = a;
}

// ---------------- cross K/V projection over HW --------------------------------
__global__ __launch_bounds__(256) void k_kv_cross(const float* __restrict__ feat,
    const float* __restrict__ kpeT, const float* __restrict__ w,
    const float* __restrict__ bias, float* __restrict__ kh, float* __restrict__ vh)
{
    __shared__ float as[32][68];
    __shared__ float wk[32][128], wv[32][128];
    const int tid = threadIdx.x, n0 = blockIdx.x * 64, b = blockIdx.y;
    const int cg = tid & 31, ng = tid >> 5;
    float ak[4][8], av[4][8];
#pragma unroll
    for (int i = 0; i < 4; ++i)
#pragma unroll
        for (int j = 0; j < 8; ++j) { ak[i][j] = 0.f; av[i][j] = 0.f; }
    for (int kc = 0; kc < 128; kc += 32) {
        for (int s = tid; s < 2048; s += 256) {
            const int k = s >> 6, n = s & 63;
            float fv = 0.f;
            if (n0 + n < HWN)
                fv = feat[((size_t)b * 128 + kc + k) * HWN + n0 + n]
                   + kpeT[(size_t)(kc + k) * HWN + n0 + n];
            as[k][n] = fv;
        }
        for (int s = tid; s < 4096; s += 256) {
            const int k = s >> 7, c = s & 127;
            wk[k][c] = w[(128 + kc + k) * 128 + c];
            wv[k][c] = w[(256 + kc + k) * 128 + c];
        }
        __syncthreads();
#pragma unroll
        for (int k = 0; k < 32; ++k) {
            const float4 x0 = *(const float4*)&as[k][ng * 8];
            const float4 x1 = *(const float4*)&as[k][ng * 8 + 4];
            const float4 wk4 = *(const float4*)&wk[k][cg * 4];
            const float4 wv4 = *(const float4*)&wv[k][cg * 4];
            float xv[8] = {x0.x, x0.y, x0.z, x0.w, x1.x, x1.y, x1.z, x1.w};
#pragma unroll
            for (int j = 0; j < 8; ++j) {
                ak[0][j] += wk4.x * xv[j]; ak[1][j] += wk4.y * xv[j];
                ak[2][j] += wk4.z * xv[j]; ak[3][j] += wk4.w * xv[j];
                av[0][j] += wv4.x * xv[j]; av[1][j] += wv4.y * xv[j];
                av[2][j] += wv4.z * xv[j]; av[3][j] += wv4.w * xv[j];
            }
        }
        __syncthreads();
    }
    const float bk0 = bias[128 + cg * 4], bk1 = bias[128 + cg * 4 + 1];
    const float bk2 = bias[128 + cg * 4 + 2], bk3 = bias[128 + cg * 4 + 3];
    const float bv0 = bias[256 + cg * 4], bv1 = bias[256 + cg * 4 + 1];
    const float bv2 = bias[256 + cg * 4 + 2], bv3 = bias[256 + cg * 4 + 3];
#pragma unroll
    for (int j = 0; j < 8; ++j) {
        const int n = n0 + ng * 8 + j;
        if (n < HWN) {
            float4 ko = make_float4(ak[0][j] + bk0, ak[1][j] + bk1, ak[2][j] + bk2, ak[3][j] + bk3);
            float4 vo = make_float4(av[0][j] + bv0, av[1][j] + bv1, av[2][j] + bv2, av[3][j] + bv3);
            *(float4*)(kh + ((size_t)b * HWN + n) * 128 + cg * 4) = ko;
            *(float4*)(vh + ((size_t)b * HWN + n) * 128 + cg * 4) = vo;
        }
    }
}

// ---------------- flash cross-attention, split-K ------------------------------
#define KSPLIT 16
__global__ __launch_bounds__(256) void k_flash(const float* __restrict__ qh,
    const float* __restrict__ kh, const float* __restrict__ vh,
    float* __restrict__ o_part, float* __restrict__ m_part, float* __restrict__ l_part)
{
    __shared__ float ksm[64][16];
    __shared__ float vsm[64][16];
    const int bh = blockIdx.x, rt = blockIdx.y, ksid = blockIdx.z;
    const int b = bh >> 3, h = bh & 7;
    const int tid = threadIdx.x;
    const int wave = tid >> 6, lane = tid & 63;
    const int r2 = lane >> 2, qd = lane & 3;
    const int row0 = rt * 128 + wave * 32 + r2 * 2;
    float q0r[16], q1r[16];
    {
        const bool a0 = row0 < 200, a1 = row0 + 1 < 200;
#pragma unroll
        for (int d = 0; d < 16; ++d) {
            q0r[d] = a0 ? qh[((size_t)b * 200 + row0) * 128 + h * 16 + d] * 0.25f : 0.f;
            q1r[d] = a1 ? qh[((size_t)b * 200 + row0 + 1) * 128 + h * 16 + d] * 0.25f : 0.f;
        }
    }
    const int nBase = ksid * (HWN / KSPLIT), nEnd = nBase + (HWN / KSPLIT);
    float m0 = -1e30f, m1 = -1e30f, l0 = 0.f, l1 = 0.f;
    float acc0[16], acc1[16];
#pragma unroll
    for (int d = 0; d < 16; ++d) { acc0[d] = 0.f; acc1[d] = 0.f; }
    for (int c0 = nBase; c0 < nEnd; c0 += 64) {
        const int cnt = (nEnd - c0 < 64) ? (nEnd - c0) : 64;
        __syncthreads();
        {
            const int n = tid >> 2, d0 = (tid & 3) << 2;
            float4 kv = make_float4(0, 0, 0, 0), vv = make_float4(0, 0, 0, 0);
            if (n < cnt) {
                kv = *(const float4*)(kh + ((size_t)b * HWN + c0 + n) * 128 + h * 16 + d0);
                vv = *(const float4*)(vh + ((size_t)b * HWN + c0 + n) * 128 + h * 16 + d0);
            }
            *(float4*)(&ksm[n][d0]) = kv;
            *(float4*)(&vsm[n][d0]) = vv;
        }
        __syncthreads();
        float s0[16], s1[16];
        float cm0 = -1e30f, cm1 = -1e30f;
#pragma unroll
        for (int jj = 0; jj < 16; ++jj) {
            const int j = (jj << 2) | qd;
            float t0 = 0.f, t1 = 0.f;
#pragma unroll
            for (int d = 0; d < 16; ++d) {
                const float kvv = ksm[j][d];
                t0 += q0r[d] * kvv; t1 += q1r[d] * kvv;
            }
            const bool valid = j < cnt;
            t0 = valid ? t0 : -1e30f;
            t1 = valid ? t1 : -1e30f;
            s0[jj] = t0; s1[jj] = t1;
            cm0 = fmaxf(cm0, t0); cm1 = fmaxf(cm1, t1);
        }
        cm0 = fmaxf(cm0, __shfl_xor(cm0, 1)); cm0 = fmaxf(cm0, __shfl_xor(cm0, 2));
        cm1 = fmaxf(cm1, __shfl_xor(cm1, 1)); cm1 = fmaxf(cm1, __shfl_xor(cm1, 2));
        const float mn0 = fmaxf(m0, cm0), mn1 = fmaxf(m1, cm1);
        const float cr0 = __expf(m0 - mn0), cr1 = __expf(m1 - mn1);
        l0 *= cr0; l1 *= cr1;
#pragma unroll
        for (int d = 0; d < 16; ++d) { acc0[d] *= cr0; acc1[d] *= cr1; }
#pragma unroll
        for (int jj = 0; jj < 16; ++jj) {
            const int j = (jj << 2) | qd;
            const float p0 = __expf(s0[jj] - mn0);
            const float p1 = __expf(s1[jj] - mn1);
            l0 += p0; l1 += p1;
#pragma unroll
            for (int d = 0; d < 16; ++d) {
                const float vvv = vsm[j][d];
                acc0[d] += p0 * vvv; acc1[d] += p1 * vvv;
            }
        }
        m0 = mn0; m1 = mn1;
    }
    l0 += __shfl_xor(l0, 1); l0 += __shfl_xor(l0, 2);
    l1 += __shfl_xor(l1, 1); l1 += __shfl_xor(l1, 2);
#pragma unroll
    for (int d = 0; d < 16; ++d) {
        acc0[d] += __shfl_xor(acc0[d], 1); acc0[d] += __shfl_xor(acc0[d], 2);
        acc1[d] += __shfl_xor(acc1[d], 1); acc1[d] += __shfl_xor(acc1[d], 2);
    }
    if (qd == 0) {
        const size_t pbase = ((size_t)bh * KSPLIT + ksid) * 200;
        if (row0 < 200) {
#pragma unroll
            for (int d = 0; d < 16; ++d) o_part[(pbase + row0) * 16 + d] = acc0[d];
            m_part[pbase + row0] = m0; l_part[pbase + row0] = l0;
        }
        if (row0 + 1 < 200) {
#pragma unroll
            for (int d = 0; d < 16; ++d) o_part[(pbase + row0 + 1) * 16 + d] = acc1[d];
            m_part[pbase + row0 + 1] = m1; l_part[pbase + row0 + 1] = l1;
        }
    }
}

// ---------------- merge flash splits ------------------------------------------
__global__ __launch_bounds__(64) void k_merge(const float* __restrict__ o_part,
    const float* __restrict__ m_part, const float* __restrict__ l_part,
    float* __restrict__ o_c)
{
    const int row = blockIdx.x, bh = blockIdx.y;
    const int b = bh >> 3, h = bh & 7;
    const int lane = threadIdx.x;
    float M = -1e30f;
#pragma unroll
    for (int k = 0; k < KSPLIT; ++k)
        M = fmaxf(M, m_part[((size_t)bh * KSPLIT + k) * 200 + row]);
    float L = 0.f;
#pragma unroll
    for (int k = 0; k < KSPLIT; ++k)
        L += l_part[((size_t)bh * KSPLIT + k) * 200 + row]
           * __expf(m_part[((size_t)bh * KSPLIT + k) * 200 + row] - M);
    if (lane < 16) {
        float o = 0.f;
#pragma unroll
        for (int k = 0; k < KSPLIT; ++k)
            o += o_part[(((size_t)bh * KSPLIT + k) * 200 + row) * 16 + lane]
               * __expf(m_part[((size_t)bh * KSPLIT + k) * 200 + row] - M);
        o_c[((size_t)b * 200 + row) * 128 + h * 16 + lane] = o / L;
    }
}

// ---------------- FFN + residual + LN3 ----------------------------------------
__global__ __launch_bounds__(256) void k_ffn_ln(const float* __restrict__ x,
    const float* __restrict__ w1, const float* __restrict__ b1,
    const float* __restrict__ w2, const float* __restrict__ b2,
    const float* __restrict__ g, const float* __restrict__ lb, float* __restrict__ out)
{
    __shared__ float xr[128];
    __shared__ float hs[256];
    __shared__ float rbuf[8];
    const int p = blockIdx.x, b = blockIdx.y, t = threadIdx.x;
    const size_t base = ((size_t)b * 200 + p) * 128;
    if (t < 128) xr[t] = x[base + t];
    __syncthreads();
    float hv = b1[t];
    for (int k = 0; k < 128; ++k) hv += xr[k] * w1[k * 256 + t];
    hs[t] = fmaxf(hv, 0.f);
    __syncthreads();
    float v = 0.f;
    if (t < 128) {
        v = b2[t] + xr[t];
        for (int k = 0; k < 256; ++k) v += hs[k] * w2[k * 128 + t];
    }
    float s = (t < 128) ? v : 0.f;
#pragma unroll
    for (int off = 32; off >= 1; off >>= 1) s += __shfl_xor(s, off);
    if ((t & 63) == 0) rbuf[t >> 6] = s;
    __syncthreads();
    const float mean = (rbuf[0] + rbuf[1] + rbuf[2] + rbuf[3]) * (1.f / 128.f);
    const float dv = v - mean;
    float s2 = (t < 128) ? dv * dv : 0.f;
#pragma unroll
    for (int off = 32; off >= 1; off >>= 1) s2 += __shfl_xor(s2, off);
    if ((t & 63) == 0) rbuf[4 + (t >> 6)] = s2;
    __syncthreads();
    const float var = (rbuf[4] + rbuf[5] + rbuf[6] + rbuf[7]) * (1.f / 128.f);
    if (t < 128) out[base + t] = g[t] * dv / sqrtf(var + 1e-5f) + lb[t];
}

// ---------------- separate heads: conv1 + BN + ReLU ---------------------------
__global__ __launch_bounds__(256) void k_head_h(const float* __restrict__ q3,
    const float* __restrict__ w1, const float* __restrict__ b1,
    const float* __restrict__ g, const float* __restrict__ beta,
    float* __restrict__ h_all)
{
    __shared__ float qw[128][32];
    const int pt = blockIdx.x, ih = blockIdx.y, b = blockIdx.z;
    const int tid = threadIdx.x;
    for (int s = tid; s < 4096; s += 256) {
        const int c = s & 127, wg = s >> 7;
        const int pg = pt * 24 - 1 + wg;
        qw[c][wg] = ((unsigned)pg < 200u) ? q3[((size_t)b * 200 + pg) * 128 + c] : 0.f;
    }
    __syncthreads();
    const int c = tid & 127, half = tid >> 7;
    float acc[12];
#pragma unroll
    for (int pp = 0; pp < 12; ++pp) acc[pp] = 0.f;
    const float* wbase = w1 + ((size_t)ih * 128 + c) * 384;
    for (int cin = 0; cin < 128; ++cin) {
        const float4* qp = (const float4*)&qw[cin][half * 12];
        const float4 a0 = qp[0], a1 = qp[1], a2 = qp[2], a3 = qp[3];
        float xr[16] = {a0.x, a0.y, a0.z, a0.w, a1.x, a1.y, a1.z, a1.w,
                        a2.x, a2.y, a2.z, a2.w, a3.x, a3.y, a3.z, a3.w};
        const float w0 = wbase[cin * 3], w1v = wbase[cin * 3 + 1], w2v = wbase[cin * 3 + 2];
#pragma unroll
        for (int pp = 0; pp < 12; ++pp)
            acc[pp] += xr[pp] * w0 + xr[pp + 1] * w1v + xr[pp + 2] * w2v;
    }
    const float bs = b1[ih * 128 + c], gg = g[ih * 128 + c], bt = beta[ih * 128 + c];
#pragma unroll
    for (int pp = 0; pp < 12; ++pp) {
        const int p = pt * 24 + half * 12 + pp;
        if (p < 200)
            h_all[(((size_t)b * 6 + ih) * 128 + c) * 200 + p] =
                fmaxf(gg * (acc[pp] + bs) + bt, 0.f);
    }
}

// ---------------- separate heads: conv2 + hm-score fusion ---------------------
__global__ void k_head_out(const float* __restrict__ h_all, const float* __restrict__ w2,
    const float* __restrict__ b2, const float* __restrict__ qhm, float* __restrict__ out)
{
    const int gid = blockIdx.x * 256 + threadIdx.x;
    if (gid >= 8000) return;
    const int p = gid % 200, rem = gid / 200, row = rem % 20, b = rem / 20;
    int i, oo;
    if (row < 2)       { i = 0; oo = row; }
    else if (row < 3)  { i = 1; oo = row - 2; }
    else if (row < 6)  { i = 2; oo = row - 3; }
    else if (row < 8)  { i = 3; oo = row - 6; }
    else if (row < 10) { i = 4; oo = row - 8; }
    else               { i = 5; oo = row - 10; }
    const float* hb = h_all + (((size_t)b * 6 + i) * 128) * 200;
    const float* wb = w2 + ((size_t)i * 10 + oo) * 384;
    float acc = b2[i * 10 + oo];
    for (int c = 0; c < 128; ++c) {
        const float* hr = hb + (size_t)c * 200 + p;
        const float x0 = (p > 0) ? hr[-1] : 0.f;
        const float x1 = hr[0];
        const float x2 = (p < 199) ? hr[1] : 0.f;
        acc += x0 * wb[c * 3] + x1 * wb[c * 3 + 1] + x2 * wb[c * 3 + 2];
    }
    if (i == 5) acc += qhm[((size_t)b * 10 + oo) * 200 + p];
    out[((size_t)b * 20 + row) * 200 + p] = acc;
}

// ---------------- launcher ----------------------------------------------------
extern "C" void kernel_launch(void* const* d_in, const int* in_sizes, int n_in,
                              void* d_out, int out_size, void* d_ws, size_t ws_size,
                              hipStream_t stream) {
    (void)in_sizes; (void)n_in; (void)out_size; (void)ws_size;
    const float* x        = (const float*)d_in[0];
    const float* w_shared = (const float*)d_in[1];
    const float* b_shared = (const float*)d_in[2];
    const float* w_hm1    = (const float*)d_in[3];
    const float* b_hm1    = (const float*)d_in[4];
    const float* g_hm1    = (const float*)d_in[5];
    const float* beta_hm1 = (const float*)d_in[6];
    const float* w_hm2    = (const float*)d_in[7];
    const float* b_hm2    = (const float*)d_in[8];
    const float* w_be1    = (const float*)d_in[15];
    const float* b_be1    = (const float*)d_in[16];
    const float* w_be2    = (const float*)d_in[17];
    const float* b_be2    = (const float*)d_in[18];
    const float* w_attn_s = (const float*)d_in[19];
    const float* b_attn_s = (const float*)d_in[20];
    const float* w_out_s  = (const float*)d_in[21];
    const float* b_out_s  = (const float*)d_in[22];
    const float* w_attn_c = (const float*)d_in[23];
    const float* b_attn_c = (const float*)d_in[24];
    const float* w_out_c  = (const float*)d_in[25];
    const float* b_out_c  = (const float*)d_in[26];
    const float* ln1_g    = (const float*)d_in[27];
    const float* ln1_b    = (const float*)d_in[28];
    const float* ln2_g    = (const float*)d_in[29];
    const float* ln2_b    = (const float*)d_in[30];
    const float* ln3_g    = (const float*)d_in[31];
    const float* ln3_b    = (const float*)d_in[32];
    const float* w_ff1    = (const float*)d_in[33];
    const float* b_ff1    = (const float*)d_in[34];
    const float* w_ff2    = (const float*)d_in[35];
    const float* b_ff2    = (const float*)d_in[36];
    const float* w_head1  = (const float*)d_in[37];
    const float* b_head1  = (const float*)d_in[38];
    const float* g_head1  = (const float*)d_in[39];
    const float* bt_head1 = (const float*)d_in[40];
    const float* w_head2  = (const float*)d_in[41];
    const float* b_head2  = (const float*)d_in[42];

    char* ws = (char*)d_ws;
    size_t off = 0;
    auto alloc = [&](size_t bytes) { size_t o = off; off += (bytes + 255) & ~(size_t)255; return o; };
    _Float16* wimg_s  = (_Float16*)(ws + alloc((size_t)12*9*2*4096*2));
    _Float16* wimg_h1 = (_Float16*)(ws + alloc((size_t)4*9*2*4096*2));
    float* feat   = (float*)(ws + alloc((size_t)2*128*HWN*4));
    float* bufA   = (float*)(ws + alloc((size_t)2*128*HWN*4));  // h1, later kh_c
    float* bufB   = (float*)(ws + alloc((size_t)2*128*HWN*4));  // vh_c
    float* hm_raw = (float*)(ws + alloc((size_t)2*10*HWN*4));
    float* hm_msk = (float*)(ws + alloc((size_t)2*10*HWN*4));
    float* kpeT   = (float*)(ws + alloc((size_t)128*HWN*4));
    int*   topidx = (int*)  (ws + alloc((size_t)2*200*4));
    float* q0     = (float*)(ws + alloc((size_t)2*200*128*4));
    float* qpe    = (float*)(ws + alloc((size_t)2*200*128*4));
    float* q_hm   = (float*)(ws + alloc((size_t)2*10*200*4));
    float* qh_s   = (float*)(ws + alloc((size_t)2*200*128*4));
    float* kh_s   = (float*)(ws + alloc((size_t)2*200*128*4));
    float* vh_s   = (float*)(ws + alloc((size_t)2*200*128*4));
    float* o_s    = (float*)(ws + alloc((size_t)2*200*128*4));
    float* q1n    = (float*)(ws + alloc((size_t)2*200*128*4));
    float* qh_c   = (float*)(ws + alloc((size_t)2*200*128*4));
    float* o_part = (float*)(ws + alloc((size_t)16*KSPLIT*200*16*4));
    float* m_part = (float*)(ws + alloc((size_t)16*KSPLIT*200*4));
    float* l_part = (float*)(ws + alloc((size_t)16*KSPLIT*200*4));
    float* o_c    = (float*)(ws + alloc((size_t)2*200*128*4));
    float* q2n    = (float*)(ws + alloc((size_t)2*200*128*4));
    float* q3     = (float*)(ws + alloc((size_t)2*200*128*4));
    float* h_all  = (float*)(ws + alloc((size_t)2*6*128*200*4));

    k_wsplit<<<(12*9*128*32 + 255)/256, 256, 0, stream>>>(w_shared, wimg_s, CINN);
    k_wsplit<<<(4*9*128*32 + 255)/256, 256, 0, stream>>>(w_hm1, wimg_h1, 128);
    k_kpe<<<HWN/8, 128, 0, stream>>>(w_be1, b_be1, w_be2, b_be2, kpeT);
    k_conv_mfma<384, 0><<<dim3(3, 90, 2), 256, 0, stream>>>(x, wimg_s, b_shared, nullptr, nullptr, feat);
    k_conv_mfma<128, 1><<<dim3(3, 90, 2), 256, 0, stream>>>(feat, wimg_h1, b_hm1, g_hm1, beta_hm1, bufA);
    k_convhm2<<<dim3(180, 2), 192, 0, stream>>>(bufA, w_hm2, b_hm2, hm_raw);
    k_nms<<<(2*10*HWN + 255)/256, 256, 0, stream>>>(hm_raw, hm_msk);
    k_topk<<<2, 1024, 0, stream>>>(hm_msk, topidx);
    k_gather<<<dim3(200, 2), 128, 0, stream>>>(feat, kpeT, hm_msk, topidx, q0, qpe, q_hm);
    k_proj_self<<<dim3(200, 2), 128, 0, stream>>>(q0, qpe, w_attn_s, b_attn_s, qh_s, kh_s, vh_s);
    k_attn_self<<<dim3(8, 2), 256, 0, stream>>>(qh_s, kh_s, vh_s, o_s);
    k_proj_ln<<<dim3(200, 2), 128, 0, stream>>>(o_s, w_out_s, b_out_s, q0, ln1_g, ln1_b, q1n);
    k_proj_q<<<dim3(200, 2), 128, 0, stream>>>(q1n, qpe, w_attn_c, b_attn_c, qh_c);
    k_kv_cross<<<dim3(507, 2), 256, 0, stream>>>(feat, kpeT, w_attn_c, b_attn_c, bufA, bufB);
    k_flash<<<dim3(16, 2, KSPLIT), 256, 0, stream>>>(qh_c, bufA, bufB, o_part, m_part, l_part);
    k_merge<<<dim3(200, 16), 64, 0, stream>>>(o_part, m_part, l_part, o_c);
    k_proj_ln<<<dim3(200, 2), 128, 0, stream>>>(o_c, w_out_c, b_out_c, q1n, ln2_g, ln2_b, q2n);
    k_ffn_ln<<<dim3(200, 2), 256, 0, stream>>>(q2n, w_ff1, b_ff1, w_ff2, b_ff2, ln3_g, ln3_b, q3);
    k_head_h<<<dim3(9, 6, 2), 256, 0, stream>>>(q3, w_head1, b_head1, g_head1, bt_head1, h_all);
    k_head_out<<<32, 256, 0, stream>>>(h_all, w_head2, b_head2, q_hm, (float*)d_out);
}